// Round 5
// baseline (281.995 us; speedup 1.0000x reference)
//
#include <hip/hip_runtime.h>
#include <math.h>

#define CIN    192
#define BATCH  8
#define HW     65536            // 256*256
#define HW4    16384            // float4 per (b,c) image
#define NBC    (BATCH * CIN)    // 1536
#define NDEG   3

#define SCALE_BLOCKS (CIN * 8)  // 1536 blocks per batch (8 chunks / image)
#define POOL_BLOCKS  CIN        // 192 blocks per batch (1 / image)

typedef float f4 __attribute__((ext_vector_type(4)));

__device__ __forceinline__ float gelu_exact(float x) {
    return 0.5f * x * (1.0f + erff(x * 0.70710678118654752f));
}
__device__ __forceinline__ float sigmoidf_(float x) {
    return 1.0f / (1.0f + expf(-x));
}

// One kernel, three block-roles, pipelined across batches:
//   K_i : mlp(batch i-1) | scale(batch i-2) | pool(batch i)
// Dispatch order: mlp first (longest latency chain, 1 block), then scale
// (starts the write stream), then pool (prefetches batch i into L3).
__global__ __launch_bounds__(256) void pipe_kernel(
    const float* __restrict__ x,
    const float* __restrict__ W1, const float* __restrict__ b1,
    const float* __restrict__ W2, const float* __restrict__ b2,
    const float* __restrict__ M1, const float* __restrict__ bm1,
    const float* __restrict__ M2, const float* __restrict__ bm2,
    float* __restrict__ pooled, float* __restrict__ mask,
    float* __restrict__ deg_out, float* __restrict__ out,
    int mlp_b, int scale_b, int pool_b, int nScale)
{
    const int t = threadIdx.x;
    int bid = blockIdx.x;
    const int nMlp = (mlp_b >= 0) ? 1 : 0;

    if (bid < nMlp) {
        // ---- MLP role: mask[mlp_b, :] from pooled[mlp_b, :] ----
        __shared__ float sp[CIN];
        __shared__ float sh[128];
        __shared__ float sd[NDEG];
        __shared__ float sm[64];
        const int b = mlp_b;
        if (t < CIN) sp[t] = pooled[b * CIN + t];
        __syncthreads();
        if (t < 128) {          // h = gelu(pooled @ W1 + b1)
            float a = b1[t];
#pragma unroll 4
            for (int k = 0; k < CIN; ++k) a += sp[k] * W1[k * 128 + t];
            sh[t] = gelu_exact(a);
        }
        __syncthreads();
        if (t < NDEG) {         // deg = sigmoid(h @ W2 + b2)
            float a = b2[t];
#pragma unroll 4
            for (int k = 0; k < 128; ++k) a += sh[k] * W2[k * NDEG + t];
            const float v = sigmoidf_(a);
            sd[t] = v;
            deg_out[b * NDEG + t] = v;
        }
        __syncthreads();
        if (t < 64) {           // m = gelu(deg @ M1 + bm1)
            float a = bm1[t];
#pragma unroll
            for (int d = 0; d < NDEG; ++d) a += sd[d] * M1[d * 64 + t];
            sm[t] = gelu_exact(a);
        }
        __syncthreads();
        if (t < CIN) {          // mask = sigmoid(m @ M2 + bm2)
            float a = bm2[t];
#pragma unroll 4
            for (int k = 0; k < 64; ++k) a += sm[k] * M2[k * CIN + t];
            mask[b * CIN + t] = sigmoidf_(a);
        }
        return;
    }
    bid -= nMlp;

    if (bid < nScale) {
        // ---- scale role: out[bc] = x[bc] * mask[bc], batch scale_b ----
        // x slice was pooled 2 kernels ago -> L3-resident. NT load (last use),
        // NT store (don't pollute L3).
        const int c = bid >> 3;
        const int chunk = bid & 7;
        const int bc = scale_b * CIN + c;
        const float mval = mask[bc];
        const size_t base = (size_t)bc * HW4 + (size_t)chunk * 2048;
        const f4* xp = reinterpret_cast<const f4*>(x) + base;
        f4* op = reinterpret_cast<f4*>(out) + base;
#pragma unroll
        for (int i = 0; i < 8; ++i) {
            f4 v = __builtin_nontemporal_load(xp + t + i * 256);
            v *= mval;
            __builtin_nontemporal_store(v, op + t + i * 256);
        }
        return;
    }
    bid -= nScale;

    {
        // ---- pool role: pooled[bc] = mean(x[bc]), batch pool_b ----
        // Normal (caching) loads: primes L3 for the scale 2 kernels later.
        const int bc = pool_b * CIN + bid;
        const f4* xp = reinterpret_cast<const f4*>(x) + (size_t)bc * HW4;
        float s = 0.0f;
#pragma unroll 16
        for (int i = 0; i < 64; ++i) {
            f4 v = xp[t + i * 256];
            s += (v.x + v.y) + (v.z + v.w);
        }
        for (int off = 32; off > 0; off >>= 1) s += __shfl_down(s, off, 64);
        __shared__ float ws_[4];
        if ((t & 63) == 0) ws_[t >> 6] = s;
        __syncthreads();
        if (t == 0)
            pooled[bc] = ((ws_[0] + ws_[1]) + (ws_[2] + ws_[3])) * (1.0f / 65536.0f);
    }
}

extern "C" void kernel_launch(void* const* d_in, const int* in_sizes, int n_in,
                              void* d_out, int out_size, void* d_ws, size_t ws_size,
                              hipStream_t stream) {
    const float* x   = (const float*)d_in[0];
    const float* W1  = (const float*)d_in[1];
    const float* b1  = (const float*)d_in[2];
    const float* W2  = (const float*)d_in[3];
    const float* b2  = (const float*)d_in[4];
    const float* M1  = (const float*)d_in[5];
    const float* bm1 = (const float*)d_in[6];
    const float* M2  = (const float*)d_in[7];
    const float* bm2 = (const float*)d_in[8];

    float* out0    = (float*)d_out;                  // 8*192*256*256 floats
    float* deg_out = out0 + (size_t)NBC * HW;        // 24 floats

    float* pooled = (float*)d_ws;                    // 1536 floats
    float* mask   = pooled + NBC;                    // 1536 floats

    // 3-stage pipeline over batches: K_i = mlp(i-1) | scale(i-2) | pool(i)
    for (int i = 0; i < BATCH + 2; ++i) {
        const int mlp_b   = (i >= 1 && i <= BATCH) ? (i - 1) : -1;
        const int scale_b = (i >= 2) ? (i - 2) : -1;
        const int pool_b  = (i < BATCH) ? i : -1;
        const int nMlp   = (mlp_b   >= 0) ? 1 : 0;
        const int nScale = (scale_b >= 0) ? SCALE_BLOCKS : 0;
        const int nPool  = (pool_b  >= 0) ? POOL_BLOCKS : 0;
        const int grid = nMlp + nScale + nPool;
        pipe_kernel<<<grid, 256, 0, stream>>>(
            x, W1, b1, W2, b2, M1, bm1, M2, bm2,
            pooled, mask, deg_out, out0,
            mlp_b, scale_b, pool_b, nScale);
    }
}